// Round 7
// baseline (2996.080 us; speedup 1.0000x reference)
//
#include <hip/hip_runtime.h>

// LSTM 2-layer scan: N=1024 rows, T=2048 sequential steps.
// R7 redesign: weights stream from LDS (no long-lived registers -> allocator
// AGPR-parking pathology of R1-R6 is structurally impossible), amortized over
// 4 batch rows per block. 256 blocks (1/CU) x 256 thr (4 waves).
// Lane quad = 4 gates of one hidden unit (verified R4 mapping).
// Bank math: weight row stride 52 dwords; lane dword = 52*(51g+16w+q)+4j+c,
// bank/4 window = (7g+5q+j) mod 8 -> over 64 lanes each 4-bank window gets
// exactly 8 lanes = 8 dwords/bank, perfectly uniform (no conflict).
// h reads are whole-wave same-address broadcasts (free). x transposed [t][4].
// Layer 2: wave m owns batch row m (c2/h2 wave-uniform in registers).

constexpr int H  = 51;
constexpr int TL = 2048;
constexpr int R  = 4;     // batch rows per block
constexpr int WS = 52;    // padded LDS row stride (floats), col 51 = 0

typedef float v2f __attribute__((ext_vector_type(2)));
typedef float v4f __attribute__((ext_vector_type(4)));

__device__ __forceinline__ float rcpf(float x)   { return __builtin_amdgcn_rcpf(x); }
__device__ __forceinline__ float exp2f_(float x) { return __builtin_amdgcn_exp2f(x); }

constexpr float LOG2E  = 1.442695041f;
constexpr float LOG2E2 = 2.885390082f;

template <int CTRL>
__device__ __forceinline__ float dppmov(float v) {
    return __int_as_float(__builtin_amdgcn_update_dpp(
        0, __float_as_int(v), CTRL, 0xF, 0xF, true));
}

template <int OFF>
__device__ __forceinline__ float swzb(float v) {
    return __int_as_float(__builtin_amdgcn_ds_swizzle(__float_as_int(v), OFF));
}

// full-wave sum, all 64 lanes end with the total (HW-verified R4/R5)
__device__ __forceinline__ float wave_sum(float p) {
    p += dppmov<0xB1>(p);     // quad_perm xor1
    p += dppmov<0x4E>(p);     // quad_perm xor2
    p += dppmov<0x124>(p);    // row_ror:4
    p += dppmov<0x128>(p);    // row_ror:8
    p += swzb<0x401f>(p);     // xor16
    p += __shfl_xor(p, 32, 64);
    return p;
}

template <int PAT>
__device__ __forceinline__ float quadb(float v) {
    // DPP quad_perm broadcast of quad-lane k (PAT = k*0x55)
    return __int_as_float(__builtin_amdgcn_update_dpp(
        0, __float_as_int(v), PAT, 0xF, 0xF, true));
}

__device__ __forceinline__ void pk_fma(v2f& acc, const v2f a, const v2f b) {
    asm("v_pk_fma_f32 %0, %1, %2, %0" : "+v"(acc) : "v"(a), "v"(b));
}

// layer-2 LSTM cell step for one batch row; c2/h2 are wave-uniform registers
__device__ __forceinline__ void layer2_step(
    const float* __restrict__ hpm, int lane,
    const float4& w2, const float4& wh2, const float4& b2,
    float& c2r, float& h2r, float* __restrict__ out_ptr)
{
    const float hpv = (lane < H) ? hpm[lane] : 0.0f;
    const float p0 = wave_sum(w2.x * hpv);
    const float p1 = wave_sum(w2.y * hpv);
    const float p2 = wave_sum(w2.z * hpv);
    const float p3 = wave_sum(w2.w * hpv);
    const float a0 = fmaf(wh2.x, h2r, p0) + b2.x;
    const float a1 = fmaf(wh2.y, h2r, p1) + b2.y;
    const float a2 = fmaf(wh2.z, h2r, p2) + b2.z;
    const float a3 = fmaf(wh2.w, h2r, p3) + b2.w;
    const float si = rcpf(1.0f + exp2f_(a0 * -LOG2E));
    const float sf = rcpf(1.0f + exp2f_(a1 * -LOG2E));
    const float tg = 1.0f - 2.0f * rcpf(1.0f + exp2f_(a2 * LOG2E2));
    const float so = rcpf(1.0f + exp2f_(a3 * -LOG2E));
    c2r = fmaf(sf, c2r, si * tg);
    h2r = so * (1.0f - 2.0f * rcpf(1.0f + exp2f_(c2r * LOG2E2)));
    if (lane == 0) *out_ptr = h2r;
}

__global__ void
__attribute__((amdgpu_flat_work_group_size(256, 256)))
__attribute__((amdgpu_waves_per_eu(1)))
lstm2_fused(const float* __restrict__ stim,
            const float* __restrict__ Wih1,
            const float* __restrict__ Whh1,
            const float* __restrict__ bih1,
            const float* __restrict__ bhh1,
            const float* __restrict__ Wih2,
            const float* __restrict__ Whh2,
            const float* __restrict__ bih2,
            const float* __restrict__ bhh2,
            float* __restrict__ out)
{
    const int b    = blockIdx.x;
    const int tid  = threadIdx.x;
    const int wid  = tid >> 6;                 // 0..3 == batch row owned for layer2
    const int lane = tid & 63;
    const int gate = lane & 3;                 // 0=i 1=f 2=g 3=o
    const int unit = wid * 16 + (lane >> 2);   // hidden unit, valid < 51
    const bool uval = (unit < H);
    const int r    = gate * H + unit;          // gate-row in [0,204)
    const int rs   = uval ? r : 0;             // clamped for safe LDS reads

    __shared__ __align__(16) float wlds[204 * WS];   // 42.4 KB
    __shared__ __align__(16) float xrt[TL][R];       // 32 KB, x transposed
    __shared__ __align__(16) float hb[2][R][WS];     // 1.7 KB, col51 = 0

    // ---- stage stimulus: 4 rows, coalesced read, transposed LDS write ----
    for (int m = 0; m < R; ++m) {
        const float4* s4 = reinterpret_cast<const float4*>(stim + (size_t)(b * R + m) * TL);
        for (int i = tid; i < TL / 4; i += 256) {
            const float4 v = s4[i];
            xrt[4 * i + 0][m] = v.x;
            xrt[4 * i + 1][m] = v.y;
            xrt[4 * i + 2][m] = v.z;
            xrt[4 * i + 3][m] = v.w;
        }
    }
    // ---- stage Whh1 into padded LDS rows ----
    for (int i = tid; i < 204 * H; i += 256) {
        const int rr = i / H;            // magic-mul div
        const int kk = i - rr * H;
        wlds[rr * WS + kk] = Whh1[i];
    }
    for (int i = tid; i < 204; i += 256) wlds[i * WS + H] = 0.0f;   // zero pad col
    for (int i = tid; i < 2 * R * WS; i += 256) (&hb[0][0][0])[i] = 0.0f;

    // ---- per-thread layer-1 scalars ----
    const float bsum = uval ? (bih1[r] + bhh1[r]) : 0.0f;
    const float wi1  = uval ? Wih1[r] : 0.0f;

    // ---- layer-2 weights (per-lane column + uniform scalars) ----
    float4 w2c = make_float4(
        (lane < H) ? Wih2[0 * H + lane] : 0.0f,
        (lane < H) ? Wih2[1 * H + lane] : 0.0f,
        (lane < H) ? Wih2[2 * H + lane] : 0.0f,
        (lane < H) ? Wih2[3 * H + lane] : 0.0f);
    float4 wh2c = make_float4(Whh2[0], Whh2[1], Whh2[2], Whh2[3]);
    float4 b2c  = make_float4(bih2[0] + bhh2[0], bih2[1] + bhh2[1],
                              bih2[2] + bhh2[2], bih2[3] + bhh2[3]);

    float c2r = 0.0f, h2r = 0.0f;                       // wave-uniform layer-2 state
    float* out_row = out + (size_t)(b * R + wid) * TL;  // wave's own output row

    float c1_0 = 0.0f, c1_1 = 0.0f, c1_2 = 0.0f, c1_3 = 0.0f;
    const float* wrow = wlds + rs * WS;

    __syncthreads();

    for (int t = 0; t < TL; ++t) {
        const int pe = (t & 1) ^ 1;
        const float* hp0 = &hb[pe][0][0];
        const float* hp1 = &hb[pe][1][0];
        const float* hp2 = &hb[pe][2][0];
        const float* hp3 = &hb[pe][3][0];

        // ---- layer 2 for step t-1: wave m handles batch row m ----
        if (t > 0) {
            layer2_step(&hb[pe][wid][0], lane, w2c, wh2c, b2c, c2r, h2r,
                        out_row + (t - 1));
        }

        // ---- layer 1: 4 rows, weights streamed from LDS (13 b128) ----
        v2f a00 = {0,0}, a01 = {0,0}, a10 = {0,0}, a11 = {0,0};
        v2f a20 = {0,0}, a21 = {0,0}, a30 = {0,0}, a31 = {0,0};
        #define DOTJ(J) { \
            const v4f wv = *reinterpret_cast<const v4f*>(wrow + 4*(J)); \
            const v2f wlo = __builtin_shufflevector(wv, wv, 0, 1); \
            const v2f whi = __builtin_shufflevector(wv, wv, 2, 3); \
            const v4f h0v = *reinterpret_cast<const v4f*>(hp0 + 4*(J)); \
            const v4f h1v = *reinterpret_cast<const v4f*>(hp1 + 4*(J)); \
            const v4f h2v = *reinterpret_cast<const v4f*>(hp2 + 4*(J)); \
            const v4f h3v = *reinterpret_cast<const v4f*>(hp3 + 4*(J)); \
            pk_fma(a00, wlo, __builtin_shufflevector(h0v, h0v, 0, 1)); \
            pk_fma(a01, whi, __builtin_shufflevector(h0v, h0v, 2, 3)); \
            pk_fma(a10, wlo, __builtin_shufflevector(h1v, h1v, 0, 1)); \
            pk_fma(a11, whi, __builtin_shufflevector(h1v, h1v, 2, 3)); \
            pk_fma(a20, wlo, __builtin_shufflevector(h2v, h2v, 0, 1)); \
            pk_fma(a21, whi, __builtin_shufflevector(h2v, h2v, 2, 3)); \
            pk_fma(a30, wlo, __builtin_shufflevector(h3v, h3v, 0, 1)); \
            pk_fma(a31, whi, __builtin_shufflevector(h3v, h3v, 2, 3)); }
        DOTJ(0) DOTJ(1) DOTJ(2) DOTJ(3) DOTJ(4) DOTJ(5) DOTJ(6)
        DOTJ(7) DOTJ(8) DOTJ(9) DOTJ(10) DOTJ(11) DOTJ(12)
        #undef DOTJ

        const v4f xv = *reinterpret_cast<const v4f*>(&xrt[t][0]);  // x for 4 rows
        const float aa0 = (a00.x + a00.y) + (a01.x + a01.y) + fmaf(xv.x, wi1, bsum);
        const float aa1 = (a10.x + a10.y) + (a11.x + a11.y) + fmaf(xv.y, wi1, bsum);
        const float aa2 = (a20.x + a20.y) + (a21.x + a21.y) + fmaf(xv.z, wi1, bsum);
        const float aa3 = (a30.x + a30.y) + (a31.x + a31.y) + fmaf(xv.w, wi1, bsum);

        // ---- activations + state update, per row ----
        const bool  istanh = (gate == 2);
        const float kk2 = istanh ? LOG2E2 : -LOG2E;
        #define ACT(AA, C1, MIDX) { \
            const float rr_ = rcpf(1.0f + exp2f_((AA) * kk2)); \
            const float vv  = istanh ? fmaf(-2.0f, rr_, 1.0f) : rr_; \
            const float vi = quadb<0x00>(vv); \
            const float vf = quadb<0x55>(vv); \
            const float vg = quadb<0xAA>(vv); \
            const float vo = quadb<0xFF>(vv); \
            C1 = fmaf(vf, C1, vi * vg); \
            const float tr = rcpf(1.0f + exp2f_((C1) * LOG2E2)); \
            const float h1v = vo * fmaf(-2.0f, tr, 1.0f); \
            if (uval && gate == 0) hb[t & 1][MIDX][unit] = h1v; }
        ACT(aa0, c1_0, 0)
        ACT(aa1, c1_1, 1)
        ACT(aa2, c1_2, 2)
        ACT(aa3, c1_3, 3)
        #undef ACT

        __syncthreads();   // the single per-step barrier
    }

    // ---- drain: layer 2 for t = TL-1 (h1 is in hb[1]) ----
    layer2_step(&hb[(TL & 1) ^ 1][wid][0], lane, w2c, wh2c, b2c, c2r, h2r,
                out_row + (TL - 1));
}

extern "C" void kernel_launch(void* const* d_in, const int* in_sizes, int n_in,
                              void* d_out, int out_size, void* d_ws, size_t ws_size,
                              hipStream_t stream) {
    const float* stim = (const float*)d_in[0];
    const float* Wih1 = (const float*)d_in[1];
    const float* Whh1 = (const float*)d_in[2];
    const float* bih1 = (const float*)d_in[3];
    const float* bhh1 = (const float*)d_in[4];
    const float* Wih2 = (const float*)d_in[5];
    const float* Whh2 = (const float*)d_in[6];
    const float* bih2 = (const float*)d_in[7];
    const float* bhh2 = (const float*)d_in[8];
    float* out = (float*)d_out;

    const int N = in_sizes[0] / TL;   // 1024
    lstm2_fused<<<dim3(N / R), dim3(256), 0, stream>>>(
        stim, Wih1, Whh1, bih1, bhh1, Wih2, Whh2, bih2, bhh2, out);
}

// Round 8
// 2548.993 us; speedup vs baseline: 1.1754x; 1.1754x over previous
//
#include <hip/hip_runtime.h>
#include <stdint.h>

// LSTM 2-layer scan: N=1024 rows, T=2048 sequential steps.
// R8: weights stream from LDS via REAL ds_read_b128 (asm — R7's v4f+shuffle
// compiled to ds_read_b64 pairs whose addresses are all 0 mod 4 -> even banks
// only -> 1.7e8 conflicts). Counted-lgkmcnt pipeline (issue 3 chunks ahead,
// wait lgkmcnt(9), sched_barrier after each wait per rule #18).
// R=2 rows/block, 512 blocks = 2 blocks/CU (R7's 1 block/CU had 1 wave/SIMD,
// zero latency hiding). Lane quad = 4 gates of one unit (R4-verified mapping);
// layer 2 on rotating waves with LDS c2/h2 state.

constexpr int H  = 51;
constexpr int TL = 2048;
constexpr int R  = 2;     // batch rows per block
constexpr int WS = 52;    // LDS weight/h row stride in floats (208B, 16B-mult)

typedef float v2f __attribute__((ext_vector_type(2)));
typedef float v4f __attribute__((ext_vector_type(4)));

__device__ __forceinline__ float rcpf(float x)   { return __builtin_amdgcn_rcpf(x); }
__device__ __forceinline__ float exp2f_(float x) { return __builtin_amdgcn_exp2f(x); }

constexpr float LOG2E  = 1.442695041f;
constexpr float LOG2E2 = 2.885390082f;

__device__ __forceinline__ uint32_t ldsoff(const void* p) {
    // generic->LDS byte offset: LDS aperture has zero low 32 bits
    return (uint32_t)(uintptr_t)p;
}

template <int CTRL>
__device__ __forceinline__ float dppmov(float v) {
    return __int_as_float(__builtin_amdgcn_update_dpp(
        0, __float_as_int(v), CTRL, 0xF, 0xF, true));
}

template <int OFF>
__device__ __forceinline__ float swzb(float v) {
    return __int_as_float(__builtin_amdgcn_ds_swizzle(__float_as_int(v), OFF));
}

// full-wave sum, all 64 lanes end with the total (HW-verified R4/R5)
__device__ __forceinline__ float wave_sum(float p) {
    p += dppmov<0xB1>(p);
    p += dppmov<0x4E>(p);
    p += dppmov<0x124>(p);
    p += dppmov<0x128>(p);
    p += swzb<0x401f>(p);
    p += __shfl_xor(p, 32, 64);
    return p;
}

template <int PAT>
__device__ __forceinline__ float quadb(float v) {
    return __int_as_float(__builtin_amdgcn_update_dpp(
        0, __float_as_int(v), PAT, 0xF, 0xF, true));
}

__device__ __forceinline__ void pk_fma(v2f& acc, const v2f a, const v2f b) {
    asm("v_pk_fma_f32 %0, %1, %2, %0" : "+v"(acc) : "v"(a), "v"(b));
}

__device__ __forceinline__ void layer2_step(
    const float* __restrict__ hpm, int lane,
    const float4& w2, const float4& wh2, const float4& b2,
    float* __restrict__ c2h2m, float* __restrict__ out_ptr)
{
    const float hpv = (lane < H) ? hpm[lane] : 0.0f;
    const float p0 = wave_sum(w2.x * hpv);
    const float p1 = wave_sum(w2.y * hpv);
    const float p2 = wave_sum(w2.z * hpv);
    const float p3 = wave_sum(w2.w * hpv);
    const float c2 = c2h2m[0], h2 = c2h2m[1];
    const float a0 = fmaf(wh2.x, h2, p0) + b2.x;
    const float a1 = fmaf(wh2.y, h2, p1) + b2.y;
    const float a2 = fmaf(wh2.z, h2, p2) + b2.z;
    const float a3 = fmaf(wh2.w, h2, p3) + b2.w;
    const float si = rcpf(1.0f + exp2f_(a0 * -LOG2E));
    const float sf = rcpf(1.0f + exp2f_(a1 * -LOG2E));
    const float tg = 1.0f - 2.0f * rcpf(1.0f + exp2f_(a2 * LOG2E2));
    const float so = rcpf(1.0f + exp2f_(a3 * -LOG2E));
    const float c2n = fmaf(sf, c2, si * tg);
    const float h2n = so * (1.0f - 2.0f * rcpf(1.0f + exp2f_(c2n * LOG2E2)));
    if (lane == 0) { c2h2m[0] = c2n; c2h2m[1] = h2n; *out_ptr = h2n; }
}

__global__ void
__attribute__((amdgpu_flat_work_group_size(256, 256)))
lstm2_fused(const float* __restrict__ stim,
            const float* __restrict__ Wih1,
            const float* __restrict__ Whh1,
            const float* __restrict__ bih1,
            const float* __restrict__ bhh1,
            const float* __restrict__ Wih2,
            const float* __restrict__ Whh2,
            const float* __restrict__ bih2,
            const float* __restrict__ bhh2,
            float* __restrict__ out)
{
    const int b    = blockIdx.x;
    const int tid  = threadIdx.x;
    const int wid  = tid >> 6;
    const int lane = tid & 63;
    const int gate = lane & 3;                 // 0=i 1=f 2=g 3=o
    const int unit = wid * 16 + (lane >> 2);   // hidden unit, valid < 51
    const bool uval = (unit < H);
    const int r    = gate * H + unit;
    const int rs   = uval ? r : 0;

    __shared__ __align__(16) float wlds[204 * WS];   // 42.4 KB
    __shared__ __align__(16) float xr2[TL * R];      // 16 KB, x interleaved [t][m]
    __shared__ __align__(16) float hbu[2][R][WS];    // 832 B, col 51 = 0
    __shared__ float c2h2s[R][2];

    // ---- stage stimulus: interleaved [t][m] so one b64 feeds both rows ----
    for (int m = 0; m < R; ++m) {
        const float4* s4 = reinterpret_cast<const float4*>(stim + (size_t)(b * R + m) * TL);
        for (int i = tid; i < TL / 4; i += 256) {
            const float4 v = s4[i];
            xr2[(4 * i + 0) * R + m] = v.x;
            xr2[(4 * i + 1) * R + m] = v.y;
            xr2[(4 * i + 2) * R + m] = v.z;
            xr2[(4 * i + 3) * R + m] = v.w;
        }
    }
    // ---- stage Whh1 rows (stride 52, col 51 zeroed) ----
    for (int i = tid; i < 204 * H; i += 256) {
        const int rr = i / H;
        const int kk = i - rr * H;
        wlds[rr * WS + kk] = Whh1[i];
    }
    for (int i = tid; i < 204; i += 256) wlds[i * WS + H] = 0.0f;
    if (tid < 2 * R * WS) (&hbu[0][0][0])[tid] = 0.0f;
    if (tid < R * 2)      (&c2h2s[0][0])[tid]  = 0.0f;

    // ---- per-thread layer-1 scalars ----
    const float bsum = uval ? (bih1[r] + bhh1[r]) : 0.0f;
    const float wi1  = uval ? Wih1[r] : 0.0f;

    // ---- layer-2 weights ----
    float4 w2c = make_float4(
        (lane < H) ? Wih2[0 * H + lane] : 0.0f,
        (lane < H) ? Wih2[1 * H + lane] : 0.0f,
        (lane < H) ? Wih2[2 * H + lane] : 0.0f,
        (lane < H) ? Wih2[3 * H + lane] : 0.0f);
    float4 wh2c = make_float4(Whh2[0], Whh2[1], Whh2[2], Whh2[3]);
    float4 b2c  = make_float4(bih2[0] + bhh2[0], bih2[1] + bhh2[1],
                              bih2[2] + bhh2[2], bih2[3] + bhh2[3]);

    const uint32_t wbase = ldsoff(wlds) + (uint32_t)rs * (WS * 4);
    const uint32_t hb0   = ldsoff(hbu);
    const uint32_t xb0   = ldsoff(xr2);

    float c1_0 = 0.0f, c1_1 = 0.0f;
    float* o0 = out + (size_t)(b * R + 0) * TL;
    float* o1 = out + (size_t)(b * R + 1) * TL;
    const int rot = b & 3;

    __syncthreads();

    for (int t = 0; t < TL; ++t) {
        const int pe = (t & 1) ^ 1;
        const uint32_t h0base = hb0 + (uint32_t)pe * (R * WS * 4);
        const uint32_t h1base = h0base + (WS * 4);

        // ---- x pair for this step (issued first; drained by chunk waits) ----
        v2f xv;
        asm volatile("ds_read_b64 %0, %1" : "=v"(xv) : "v"(xb0 + (uint32_t)t * 8));

        // ---- layer 2 for step t-1: rotating wave per row ----
        if (t > 0) {
            if (wid == ((t + rot) & 3))
                layer2_step(&hbu[pe][0][0], lane, w2c, wh2c, b2c, &c2h2s[0][0], o0 + (t - 1));
            if (wid == ((t + 2 + rot) & 3))
                layer2_step(&hbu[pe][1][0], lane, w2c, wh2c, b2c, &c2h2s[1][0], o1 + (t - 1));
        }

        // ---- layer 1: counted-lgkm pipelined b128 chunk stream ----
        v4f wq0, wq1, wq2, wq3, wq4, wq5, wq6, wq7, wq8, wq9, wq10, wq11, wq12;
        v4f p00, p01, p02, p03, p04, p05, p06, p07, p08, p09, p010, p011, p012;
        v4f p10, p11, p12, p13, p14, p15, p16, p17, p18, p19, p110, p111, p112;
        v2f a00 = {0.0f, 0.0f}, a01 = {0.0f, 0.0f};
        v2f a10 = {0.0f, 0.0f}, a11 = {0.0f, 0.0f};

        #define ISSUE(J, O) \
            asm volatile("ds_read_b128 %0, %1 offset:" O : "=v"(wq##J)  : "v"(wbase)); \
            asm volatile("ds_read_b128 %0, %1 offset:" O : "=v"(p0##J)  : "v"(h0base)); \
            asm volatile("ds_read_b128 %0, %1 offset:" O : "=v"(p1##J)  : "v"(h1base));
        #define CHW(J, NW) \
            asm volatile("s_waitcnt lgkmcnt(" #NW ")"); \
            __builtin_amdgcn_sched_barrier(0); \
            { const v2f wlo = __builtin_shufflevector(wq##J, wq##J, 0, 1); \
              const v2f whi = __builtin_shufflevector(wq##J, wq##J, 2, 3); \
              pk_fma(a00, wlo, __builtin_shufflevector(p0##J, p0##J, 0, 1)); \
              pk_fma(a01, whi, __builtin_shufflevector(p0##J, p0##J, 2, 3)); \
              pk_fma(a10, wlo, __builtin_shufflevector(p1##J, p1##J, 0, 1)); \
              pk_fma(a11, whi, __builtin_shufflevector(p1##J, p1##J, 2, 3)); }

        ISSUE(0, "0")  ISSUE(1, "16")  ISSUE(2, "32")  ISSUE(3, "48")
        CHW(0, 9)   ISSUE(4, "64")
        CHW(1, 9)   ISSUE(5, "80")
        CHW(2, 9)   ISSUE(6, "96")
        CHW(3, 9)   ISSUE(7, "112")
        CHW(4, 9)   ISSUE(8, "128")
        CHW(5, 9)   ISSUE(9, "144")
        CHW(6, 9)   ISSUE(10, "160")
        CHW(7, 9)   ISSUE(11, "176")
        CHW(8, 9)   ISSUE(12, "192")
        CHW(9, 9)
        CHW(10, 6)
        CHW(11, 3)
        CHW(12, 0)
        #undef ISSUE
        #undef CHW

        // ---- epilogue: per-row activation + state (x drained by lgkmcnt(0)) ----
        const bool  istanh = (gate == 2);
        const float kk2 = istanh ? LOG2E2 : -LOG2E;
        #define ACT(ALO, AHI, XS, C1, MIDX) { \
            const float aa = (ALO.x + ALO.y) + (AHI.x + AHI.y) + fmaf(XS, wi1, bsum); \
            const float rr_ = rcpf(1.0f + exp2f_(aa * kk2)); \
            const float vv  = istanh ? fmaf(-2.0f, rr_, 1.0f) : rr_; \
            const float vi = quadb<0x00>(vv); \
            const float vf = quadb<0x55>(vv); \
            const float vg = quadb<0xAA>(vv); \
            const float vo = quadb<0xFF>(vv); \
            C1 = fmaf(vf, C1, vi * vg); \
            const float tr = rcpf(1.0f + exp2f_((C1) * LOG2E2)); \
            const float h1v = vo * fmaf(-2.0f, tr, 1.0f); \
            if (uval && gate == 0) hbu[t & 1][MIDX][unit] = h1v; }
        ACT(a00, a01, xv.x, c1_0, 0)
        ACT(a10, a11, xv.y, c1_1, 1)
        #undef ACT

        __syncthreads();
    }

    // ---- drain: layer 2 for t = TL-1 ----
    {
        const int pe = (TL & 1) ^ 1;
        if (wid == ((TL + rot) & 3))
            layer2_step(&hbu[pe][0][0], lane, w2c, wh2c, b2c, &c2h2s[0][0], o0 + (TL - 1));
        if (wid == ((TL + 2 + rot) & 3))
            layer2_step(&hbu[pe][1][0], lane, w2c, wh2c, b2c, &c2h2s[1][0], o1 + (TL - 1));
    }
}

extern "C" void kernel_launch(void* const* d_in, const int* in_sizes, int n_in,
                              void* d_out, int out_size, void* d_ws, size_t ws_size,
                              hipStream_t stream) {
    const float* stim = (const float*)d_in[0];
    const float* Wih1 = (const float*)d_in[1];
    const float* Whh1 = (const float*)d_in[2];
    const float* bih1 = (const float*)d_in[3];
    const float* bhh1 = (const float*)d_in[4];
    const float* Wih2 = (const float*)d_in[5];
    const float* Whh2 = (const float*)d_in[6];
    const float* bih2 = (const float*)d_in[7];
    const float* bhh2 = (const float*)d_in[8];
    float* out = (float*)d_out;

    const int N = in_sizes[0] / TL;   // 1024
    lstm2_fused<<<dim3(N / R), dim3(256), 0, stream>>>(
        stim, Wih1, Whh1, bih1, bhh1, Wih2, Whh2, bih2, bhh2, out);
}

// Round 9
// 1552.900 us; speedup vs baseline: 1.9293x; 1.6414x over previous
//
#include <hip/hip_runtime.h>
#include <stdint.h>

// LSTM 2-layer scan: N=1024 rows, T=2048 steps. R9: MFMA redesign.
// R1-R6: long-lived per-thread weights get AGPR-parked with per-use shuttles
// (un-hintable). R7/R8: LDS weight streaming conflict- and BW-capped.
// Fix: weights as MFMA A-fragments (AGPR-native). gates(208xN)=W(208x53)xh.
// 256 blocks x 4 waves x 4 batch rows. Wave owns 52 PERMUTED rows
// (rl=13*gate+uloc, units 13w..13w+12) -> unit recombine is wave-local
// (no barrier); ONE block barrier per step (double-buffered hB).
// fp16 3-term split (A*256 so lo-parts stay normal); x&bias folded as
// K-slots 51/52. Layer 2 = 4 extra A-rows (wave3 lanes 16-31, regs 0-3).
// B-reads swizzled so each consecutive-8-lane group hits 8 distinct 16B
// windows (R8 lesson: that is the real b128 conflict rule).

constexpr int H  = 51;
constexpr int TL = 2048;

typedef _Float16 f16x8 __attribute__((ext_vector_type(8)));
typedef float    f32x4 __attribute__((ext_vector_type(4)));

__device__ __forceinline__ float rcpf(float x)   { return __builtin_amdgcn_rcpf(x); }
__device__ __forceinline__ float exp2f_(float x) { return __builtin_amdgcn_exp2f(x); }

constexpr float LOG2E  = 1.442695041f;
constexpr float LOG2E2 = 2.885390082f;
constexpr float INV256 = 0.00390625f;
constexpr float KS = -LOG2E * INV256;   // sigmoid arg scale (C is 256x)
constexpr float KT =  LOG2E2 * INV256;  // tanh arg scale

__device__ __forceinline__ uint16_t f16bits(_Float16 h) {
    union { _Float16 f; uint16_t u; } c; c.f = h; return c.u;
}

// physical k-index within a 64-slot hB row after XOR window swizzle
__device__ __forceinline__ int swzk(int k, int n) {
    return (((k >> 3) ^ (n & 7)) << 3) | (k & 7);
}

__device__ __forceinline__ float actv(float cv, bool isg2) {
    const float s = rcpf(1.0f + exp2f_(cv * (isg2 ? KT : KS)));
    return isg2 ? fmaf(-2.0f, s, 1.0f) : s;
}

__device__ __forceinline__ float sigf(float a) {
    return rcpf(1.0f + exp2f_(a * -LOG2E));
}
__device__ __forceinline__ float tanhf_(float a) {
    return fmaf(-2.0f, rcpf(1.0f + exp2f_(a * LOG2E2)), 1.0f);
}

// W-matrix source value for permuted row rl (this wave) and k-slot
__device__ float wsrc(int w, int rl, int k,
                      const float* Wih1, const float* Whh1,
                      const float* bih1, const float* bhh1,
                      const float* Wih2, const float* bih2, const float* bhh2) {
    if (rl < 52) {
        const int G = rl / 13, ul = rl % 13;
        const int u = 13 * w + ul;
        if (u >= H) return 0.0f;
        const int rho = G * H + u;
        if (k < H)   return Whh1[rho * H + k];
        if (k == 51) return Wih1[rho];
        if (k == 52) return bih1[rho] + bhh1[rho];
        return 0.0f;
    }
    if (w == 3 && rl < 56) {          // layer-2 rows
        const int G = rl - 52;
        if (k < H)   return Wih2[G * H + k];
        if (k == 52) return bih2[G] + bhh2[G];
        return 0.0f;
    }
    return 0.0f;
}

__global__ void
__attribute__((amdgpu_flat_work_group_size(256, 256)))
__attribute__((amdgpu_waves_per_eu(1)))
lstm2_mfma(const float* __restrict__ stim,
           const float* __restrict__ Wih1,
           const float* __restrict__ Whh1,
           const float* __restrict__ bih1,
           const float* __restrict__ bhh1,
           const float* __restrict__ Wih2,
           const float* __restrict__ Whh2,
           const float* __restrict__ bih2,
           const float* __restrict__ bhh2,
           float* __restrict__ out)
{
    const int b    = blockIdx.x;
    const int tid  = threadIdx.x;
    const int w    = tid >> 6;
    const int lane = tid & 63;
    const int lgrp = lane >> 4;
    const int n16  = lane & 15;

    __shared__ __align__(16) float    xT[TL][4];          // 32 KB
    __shared__ __align__(16) uint16_t hb[2][2][16][64];   // 8 KB [buf][hi/lo][n][k]
    __shared__ __align__(16) float    gact[4][4][64][4];  // 16 KB [wave][tile][lane][reg]
    __shared__ __align__(16) float    ring[64][16];       // 4 KB
    __shared__ float lds_pad[6144];                       // 24 KB: force 1 block/CU

    if (stim == nullptr) out[0] = lds_pad[tid];           // keep pad alive

    // ---- stage x transposed: wave w stages batch row w ----
    {
        const float* src = stim + (size_t)(b * 4 + w) * TL;
        for (int i = lane; i < TL; i += 64) xT[i][w] = src[i];
    }
    // ---- zero hB (both buffers, hi+lo) ----
    {
        uint32_t* hb32 = (uint32_t*)&hb[0][0][0][0];
        for (int i = tid; i < 2048; i += 256) hb32[i] = 0;
    }
    __syncthreads();
    // ---- bias slot (k=52, B=1.0h in both bufs) + x(0) slot (k=51, buf 0) ----
    if (tid < 4) {
        const int n = tid;
        hb[0][0][n][swzk(52, n)] = 0x3C00;   // 1.0h
        hb[1][0][n][swzk(52, n)] = 0x3C00;
        const float xv = xT[0][n];
        const _Float16 xh = (_Float16)xv;
        const _Float16 xl = (_Float16)(xv - (float)xh);
        hb[0][0][n][swzk(51, n)] = f16bits(xh);
        hb[0][1][n][swzk(51, n)] = f16bits(xl);
    }

    // ---- build A-fragments (scaled x256, hi/lo), k-contiguous-8 per lane ----
    f16x8 Ah[4][2], Al[4][2];
    #pragma unroll
    for (int jt = 0; jt < 4; ++jt) {
        #pragma unroll
        for (int kp = 0; kp < 2; ++kp) {
            f16x8 vh{}, vl{};
            #pragma unroll
            for (int j = 0; j < 8; ++j) {
                const int rl = 16 * jt + n16;              // A row: m = lane&15
                const int k  = 32 * kp + 8 * lgrp + j;     // same pi as B reads
                const float v = 256.0f * wsrc(w, rl, k, Wih1, Whh1, bih1, bhh1,
                                              Wih2, bih2, bhh2);
                const _Float16 hi = (_Float16)v;
                vh[j] = hi;
                vl[j] = (_Float16)(v - (float)hi);
            }
            Ah[jt][kp] = vh;
            Al[jt][kp] = vl;
        }
    }

    // ---- istanh mask per (tile, reg): C row rl = 16*jt + 4*lgrp + r ----
    uint32_t amask = 0;
    #pragma unroll
    for (int jt = 0; jt < 4; ++jt)
        #pragma unroll
        for (int r = 0; r < 4; ++r) {
            const int rl = 16 * jt + 4 * lgrp + r;
            if (rl >= 26 && rl < 39) amask |= (1u << (jt * 4 + r));
        }

    // ---- update-lane setup: lane<52 owns (uloc=lane>>2, n=lane&3) ----
    const int  ul   = lane >> 2;
    const int  un   = lane & 3;
    const int  uu   = 13 * w + ul;
    const bool upd  = (lane < 52) && (uu < H);
    const float* gp0; const float* gp1; const float* gp2; const float* gp3;
    {
        const int rl0 = ul,      rl1 = 13 + ul, rl2 = 26 + ul, rl3 = 39 + ul;
        gp0 = &gact[w][rl0 >> 4][((rl0 >> 2) & 3) * 16 + un][rl0 & 3];
        gp1 = &gact[w][rl1 >> 4][((rl1 >> 2) & 3) * 16 + un][rl1 & 3];
        gp2 = &gact[w][rl2 >> 4][((rl2 >> 2) & 3) * 16 + un][rl2 & 3];
        gp3 = &gact[w][rl3 >> 4][((rl3 >> 2) & 3) * 16 + un][rl3 & 3];
    }

    // layer-2 constants (uniform scalars)
    const float wh2_0 = Whh2[0], wh2_1 = Whh2[1], wh2_2 = Whh2[2], wh2_3 = Whh2[3];
    const bool  isL2  = (w == 3) && (lgrp == 1);

    const uint32_t hbbase = (uint32_t)(uintptr_t)&hb[0][0][0][0];
    const uint32_t sw     = (uint32_t)(n16 & 7);
    const uint32_t rowoff = (uint32_t)n16 * 128u;

    float c1 = 0.0f, c2 = 0.0f, h2 = 0.0f;
    __syncthreads();

    for (int t = 0; t <= TL; ++t) {
        // ---- B-fragment reads (buf t&1): swizzled windows, consecutive-8 safe ----
        const uint32_t rb = hbbase + ((t & 1) ? 4096u : 0u) + rowoff;
        const uint32_t a0 = rb + ((((uint32_t)lgrp) ^ sw) << 4);
        const uint32_t a1 = rb + (((((uint32_t)lgrp) ^ sw) ^ 4u) << 4);
        f16x8 bh0, bl0, bh1, bl1;
        asm volatile("ds_read_b128 %0, %1"             : "=v"(bh0) : "v"(a0));
        asm volatile("ds_read_b128 %0, %1 offset:2048" : "=v"(bl0) : "v"(a0));
        asm volatile("ds_read_b128 %0, %1"             : "=v"(bh1) : "v"(a1));
        asm volatile("ds_read_b128 %0, %1 offset:2048" : "=v"(bl1) : "v"(a1));
        asm volatile("s_waitcnt lgkmcnt(0)" ::: "memory");
        __builtin_amdgcn_sched_barrier(0);

        // ---- MFMA: 4 tiles x (3-term x 2 K-halves) ----
        f32x4 C0{}, C1{}, C2{}, C3{};
        #define TILE(CV, JT) \
            CV = __builtin_amdgcn_mfma_f32_16x16x32_f16(Ah[JT][0], bh0, CV, 0, 0, 0); \
            CV = __builtin_amdgcn_mfma_f32_16x16x32_f16(Al[JT][0], bh0, CV, 0, 0, 0); \
            CV = __builtin_amdgcn_mfma_f32_16x16x32_f16(Ah[JT][0], bl0, CV, 0, 0, 0); \
            CV = __builtin_amdgcn_mfma_f32_16x16x32_f16(Ah[JT][1], bh1, CV, 0, 0, 0); \
            CV = __builtin_amdgcn_mfma_f32_16x16x32_f16(Al[JT][1], bh1, CV, 0, 0, 0); \
            CV = __builtin_amdgcn_mfma_f32_16x16x32_f16(Ah[JT][1], bl1, CV, 0, 0, 0);
        TILE(C0, 0) TILE(C1, 1) TILE(C2, 2) TILE(C3, 3)
        #undef TILE

        // ---- activation + wave-local gact write (lane-linear b128) ----
        #define ACT(CV, JT) { \
            f32x4 av; \
            av[0] = actv(CV[0], (amask >> (JT * 4 + 0)) & 1); \
            av[1] = actv(CV[1], (amask >> (JT * 4 + 1)) & 1); \
            av[2] = actv(CV[2], (amask >> (JT * 4 + 2)) & 1); \
            av[3] = actv(CV[3], (amask >> (JT * 4 + 3)) & 1); \
            *(f32x4*)&gact[w][JT][lane][0] = av; }
        ACT(C0, 0) ACT(C1, 1) ACT(C2, 2) ACT(C3, 3)
        #undef ACT

        // ---- unit update: wave-local gact read (compiler orders lgkmcnt) ----
        const int wb = (t + 1) & 1;
        if (upd) {
            const float si = *gp0, sf = *gp1, tg = *gp2, so = *gp3;
            c1 = fmaf(sf, c1, si * tg);
            const float h1 = so * tanhf_(c1);
            const _Float16 hh = (_Float16)h1;
            const _Float16 hl = (_Float16)(h1 - (float)hh);
            const int kp = swzk(uu, un);
            hb[wb][0][un][kp] = f16bits(hh);
            hb[wb][1][un][kp] = f16bits(hl);
        }
        // ---- x(t+1) slot writers ----
        if (w == 0 && lane >= 52 && lane < 56) {
            const int n  = lane - 52;
            const int tt = (t + 1 < TL) ? (t + 1) : (TL - 1);
            const float xv = xT[tt][n];
            const _Float16 xh = (_Float16)xv;
            const _Float16 xl = (_Float16)(xv - (float)xh);
            const int kp = swzk(51, n);
            hb[wb][0][n][kp] = f16bits(xh);
            hb[wb][1][n][kp] = f16bits(xl);
        }
        // ---- layer 2: wave3 lanes 16-31 hold rows 52-55 in C3 regs 0-3 ----
        if (isL2 && t >= 1) {
            const float a0 = fmaf(wh2_0, h2, C3[0] * INV256);
            const float a1 = fmaf(wh2_1, h2, C3[1] * INV256);
            const float a2 = fmaf(wh2_2, h2, C3[2] * INV256);
            const float a3 = fmaf(wh2_3, h2, C3[3] * INV256);
            c2 = fmaf(sigf(a1), c2, sigf(a0) * tanhf_(a2));
            h2 = sigf(a3) * tanhf_(c2);
            ring[(t - 1) & 63][n16] = h2;
        }

        __syncthreads();

        // ---- ring flush every 64 steps (uniform condition) ----
        if (t >= 64 && (t & 63) == 0) {
            const int n = tid >> 6, j = tid & 63;
            out[(size_t)(b * 4 + n) * TL + (t - 64) + j] = ring[j][n];
            __syncthreads();
        }
    }
}

extern "C" void kernel_launch(void* const* d_in, const int* in_sizes, int n_in,
                              void* d_out, int out_size, void* d_ws, size_t ws_size,
                              hipStream_t stream) {
    const float* stim = (const float*)d_in[0];
    const float* Wih1 = (const float*)d_in[1];
    const float* Whh1 = (const float*)d_in[2];
    const float* bih1 = (const float*)d_in[3];
    const float* bhh1 = (const float*)d_in[4];
    const float* Wih2 = (const float*)d_in[5];
    const float* Whh2 = (const float*)d_in[6];
    const float* bih2 = (const float*)d_in[7];
    const float* bhh2 = (const float*)d_in[8];
    float* out = (float*)d_out;

    const int N = in_sizes[0] / TL;   // 1024
    lstm2_mfma<<<dim3(N / 4), dim3(256), 0, stream>>>(
        stim, Wih1, Whh1, bih1, bhh1, Wih2, Whh2, bih2, bhh2, out);
}